// Round 11
// baseline (20.430 us; speedup 1.0000x reference)
//
#include <hip/hip_runtime.h>
#include <math.h>

#define NLAB 2000
#define BATCH 1024
#define LAMBDA_SMOOTH 0.1f

#define RPG 16           // batch rows per group
#define NRG 64           // row groups (1024/16)
#define ES 8             // edge slices in K2
#define NB2 512          // K2 grid = 64 rg x 8 es  (2 blocks/CU, 100% occ)
#define IMG_U16 32496    // 2000*16 + 62 pad-granules * 8 u16 = 64992 B
#define IMG_V4  4062     // same in uint4 (64992/16)

typedef _Float16 h2 __attribute__((ext_vector_type(2)));

// u16 slot of (label l, row 0): 16 u16 per label + one 16B pad granule per
// 32 labels -> gather start positions cover 8 distinct bank-quads.
__device__ __forceinline__ int slot16(int l) { return (l << 4) + ((l >> 5) << 3); }

// one packed sub + one v_dot2_f32_f16: accumulates (a-b).(a-b) for 2 rows
__device__ __forceinline__ float dot_acc(unsigned ua, unsigned ub, float acc) {
    const h2 a = __builtin_bit_cast(h2, ua);
    const h2 b = __builtin_bit_cast(h2, ub);
    const h2 d = a - b;
    return __builtin_amdgcn_fdot2(d, d, acc, false);
}

// ---------------------------------------------------------------------------
// K1: convert + pack (f16). grid 512: rg = bid>>3, slice = bid&7 (250 labels).
// (unchanged from R10)
// ---------------------------------------------------------------------------
__global__ __launch_bounds__(256) void convert_pack_kernel(
        const float* __restrict__ logits, const float* __restrict__ labels,
        ushort* __restrict__ yPack) {
    const int rg = blockIdx.x >> 3;
    const int s  = blockIdx.x & 7;
    const int t  = threadIdx.x;
    if (t >= 250) return;
    const int l = s * 250 + t;

    unsigned p[8];
#pragma unroll
    for (int h = 0; h < 8; ++h) {
        float y2[2];
#pragma unroll
        for (int q = 0; q < 2; ++q) {
            const int r   = 2 * h + q;
            const int idx = (rg * RPG + r) * NLAB + l;   // coalesced in t
            const float lg  = logits[idx];
            const float lab = labels[idx];
            const float sg  = 1.0f / (1.0f + __expf(-lg));
            const bool ann  = (lab == 0.0f) || (lab == 1.0f);
            y2[q] = ann ? (2.0f * lab - 1.0f) : (2.0f * sg - 1.0f);
        }
        h2 hv;
        hv.x = (_Float16)y2[0];
        hv.y = (_Float16)y2[1];
        p[h] = __builtin_bit_cast(unsigned, hv);
    }
    ushort* dst = yPack + (size_t)rg * IMG_U16 + slot16(l);
    uint4 v0; v0.x = p[0]; v0.y = p[1]; v0.z = p[2]; v0.w = p[3];
    uint4 v1; v1.x = p[4]; v1.y = p[5]; v1.z = p[6]; v1.w = p[7];
    *(uint4*)(dst)     = v0;    // rows 0-7
    *(uint4*)(dst + 8) = v1;    // rows 8-15
}

// ---------------------------------------------------------------------------
// K2: edge reduction, UNDIRECTED halving.
//   Adjacency is symmetric with w_ij == w_ji, so only edges with l < r are
//   processed (contribution doubled in the final scale). Inactive lanes are
//   exec-masked off the ds_reads -> LDS gather traffic halves.
//   Load balance: 64-edge chunks are dealt round-robin to the 128 waves of
//   each rg (chunk c -> wave c%128), so every wave sees a uniform l/r mix
//   (contiguous chunks keep the sorted-left broadcast intact).
//   Pipeline: indices 2 chunks ahead, LDS data 1 chunk ahead (predicated).
// ---------------------------------------------------------------------------
__global__ __launch_bounds__(1024, 8) void edge_reduce_kernel(
        const ushort* __restrict__ yPack, const float* __restrict__ ew,
        const int* __restrict__ li, const int* __restrict__ ri,
        int nEdges, float* __restrict__ partials) {
    __shared__ uint4 shv[IMG_V4];               // 64992 B
    __shared__ float red[16];
    const int x    = blockIdx.x & 7;            // XCD slot
    const int jb   = blockIdx.x >> 3;
    const int rg   = x * 8 + (jb & 7);
    const int es   = jb >> 3;
    const int tid  = threadIdx.x;
    const int lane = tid & 63;

    const uint4* src = (const uint4*)(yPack + (size_t)rg * IMG_U16);
    for (int i = tid; i < IMG_V4; i += 1024) shv[i] = src[i];
    __syncthreads();
    const ushort* sh = (const ushort*)shv;

    const int nch   = (nEdges + 63) >> 6;       // 64-edge chunks
    const int wj    = es * 16 + (tid >> 6);     // wave id within rg: 0..127
    const int niter = (wj < nch) ? (((nch - 1 - wj) >> 7) + 1) : 0;

    float acc = 0.0f;
    int   lC = 0, rC = 1;  float wC = 0.0f;     // current chunk indices
    int   lN = 0, rN = 1;  float wN = 0.0f;     // next chunk indices
    uint4 A0, A1, B0, B1, An0, An1, Bn0, Bn1;

    // ---- prologue ----
    if (niter > 0) {
        const int e  = (wj << 6) + lane;
        const int ec = min(e, nEdges - 1);
        const int l = li[ec], r = ri[ec];
        lC = l; rC = r;
        wC = ((e < nEdges) && (l < r)) ? ew[ec] : 0.0f;
    }
    {   // stage-0 data: unconditional (clamped labels are always valid)
        const int sl = slot16(lC), sr = slot16(rC);
        A0 = *(const uint4*)(sh + sl);  A1 = *(const uint4*)(sh + sl + 8);
        B0 = *(const uint4*)(sh + sr);  B1 = *(const uint4*)(sh + sr + 8);
    }
    if (niter > 1) {
        const int e  = ((wj + 128) << 6) + lane;
        const int ec = min(e, nEdges - 1);
        const int l = li[ec], r = ri[ec];
        lN = l; rN = r;
        wN = ((e < nEdges) && (l < r)) ? ew[ec] : 0.0f;
    }
    An0 = A0; An1 = A1; Bn0 = B0; Bn1 = B1;

    for (int k = 0; k < niter; ++k) {
        // fetch indices for chunk k+2 (wave-uniform branch)
        int l2 = lN, r2 = rN; float w2 = 0.0f;
        if (k + 2 < niter) {
            const int e  = ((wj + ((k + 2) << 7)) << 6) + lane;
            const int ec = min(e, nEdges - 1);
            l2 = li[ec]; r2 = ri[ec];
            w2 = ((e < nEdges) && (l2 < r2)) ? ew[ec] : 0.0f;
        }
        // issue LDS reads for chunk k+1, exec-masked to active lanes only
        if (k + 1 < niter) {
            if (wN != 0.0f) {                   // per-lane predicate
                const int sl = slot16(lN), sr = slot16(rN);
                An0 = *(const uint4*)(sh + sl);  An1 = *(const uint4*)(sh + sl + 8);
                Bn0 = *(const uint4*)(sh + sr);  Bn1 = *(const uint4*)(sh + sr + 8);
            }
        }
        // compute current chunk: 16 rows = 8 packed dot2s (w==0 kills garbage)
        float s = 0.0f;
        s = dot_acc(A0.x, B0.x, s);
        s = dot_acc(A0.y, B0.y, s);
        s = dot_acc(A0.z, B0.z, s);
        s = dot_acc(A0.w, B0.w, s);
        s = dot_acc(A1.x, B1.x, s);
        s = dot_acc(A1.y, B1.y, s);
        s = dot_acc(A1.z, B1.z, s);
        s = dot_acc(A1.w, B1.w, s);
        acc = fmaf(wC, s, acc);

        // rotate pipeline
        wC = wN; wN = w2;
        lN = l2; rN = r2;
        A0 = An0; A1 = An1; B0 = Bn0; B1 = Bn1;
    }

#pragma unroll
    for (int off = 32; off > 0; off >>= 1)
        acc += __shfl_down(acc, off, 64);
    if ((tid & 63) == 0) red[tid >> 6] = acc;
    __syncthreads();
    if (tid == 0) {
        float t = 0.0f;
#pragma unroll
        for (int i = 0; i < 16; ++i) t += red[i];
        partials[blockIdx.x] = t;
    }
}

// ---------------------------------------------------------------------------
// K3: sum partials, scale. Single block, fixed order -> deterministic.
// ---------------------------------------------------------------------------
__global__ __launch_bounds__(512) void final_reduce_kernel(
        const float* __restrict__ partials, int n, float scale,
        float* __restrict__ out) {
    float s = 0.0f;
    for (int i = threadIdx.x; i < n; i += blockDim.x) s += partials[i];
#pragma unroll
    for (int off = 32; off > 0; off >>= 1)
        s += __shfl_down(s, off, 64);

    __shared__ float smem[8];
    const int wave = threadIdx.x >> 6;
    const int lane = threadIdx.x & 63;
    if (lane == 0) smem[wave] = s;
    __syncthreads();
    if (threadIdx.x == 0) {
        float t = 0.0f;
        for (int i = 0; i < (int)(blockDim.x >> 6); ++i) t += smem[i];
        out[0] = scale * t;
    }
}

// ---------------------------------------------------------------------------
extern "C" void kernel_launch(void* const* d_in, const int* in_sizes, int n_in,
                              void* d_out, int out_size, void* d_ws, size_t ws_size,
                              hipStream_t stream) {
    const float* logits = (const float*)d_in[0];
    const float* labels = (const float*)d_in[1];
    const float* ew     = (const float*)d_in[2];
    const int*   li     = (const int*)d_in[3];
    const int*   ri     = (const int*)d_in[4];
    float* out          = (float*)d_out;

    const int nEdges = in_sizes[2];

    // workspace: yPack images (64 * 64992 B = 4.16 MB), partials (2 KB)
    ushort* yPack    = (ushort*)d_ws;
    float*  partials = (float*)((char*)d_ws + (size_t)NRG * IMG_U16 * sizeof(ushort));

    convert_pack_kernel<<<NRG * 8, 256, 0, stream>>>(logits, labels, yPack);

    edge_reduce_kernel<<<NB2, 1024, 0, stream>>>(yPack, ew, li, ri, nEdges, partials);

    // x2: each undirected pair is counted once in K2 but twice in the mean
    const float scale = 2.0f * LAMBDA_SMOOTH / ((float)BATCH * (float)nEdges);
    final_reduce_kernel<<<1, 512, 0, stream>>>(partials, NB2, scale, out);
}

// Round 12
// 18.291 us; speedup vs baseline: 1.1169x; 1.1169x over previous
//
#include <hip/hip_runtime.h>
#include <math.h>

#define NLAB 2000
#define BATCH 1024
#define LAMBDA_SMOOTH 0.1f

#define RPG 16           // batch rows per group
#define NRG 64           // row groups (1024/16)
#define ES 8             // edge slices in K2
#define NB2 512          // K2 grid = 64 rg x 8 es  (2 blocks/CU, 100% occ)
#define IMG_U16 32496    // 2000*16 + 62 pad-granules * 8 u16 = 64992 B
#define IMG_V4  4062     // same in uint4 (64992/16)

typedef _Float16 h2 __attribute__((ext_vector_type(2)));

// u16 slot of (label l, row 0): 16 u16 per label + one 16B pad granule per
// 32 labels -> gather start positions cover 8 distinct bank-quads.
__device__ __forceinline__ int slot16(int l) { return (l << 4) + ((l >> 5) << 3); }

// one packed sub + one v_dot2_f32_f16: accumulates (a-b).(a-b) for 2 rows
__device__ __forceinline__ float dot_acc(unsigned ua, unsigned ub, float acc) {
    const h2 a = __builtin_bit_cast(h2, ua);
    const h2 b = __builtin_bit_cast(h2, ub);
    const h2 d = a - b;
    return __builtin_amdgcn_fdot2(d, d, acc, false);
}

// ---------------------------------------------------------------------------
// K1: convert + pack (f16). grid 512: rg = bid>>3, slice = bid&7 (250 labels).
// (unchanged from R10)
// ---------------------------------------------------------------------------
__global__ __launch_bounds__(256) void convert_pack_kernel(
        const float* __restrict__ logits, const float* __restrict__ labels,
        ushort* __restrict__ yPack) {
    const int rg = blockIdx.x >> 3;
    const int s  = blockIdx.x & 7;
    const int t  = threadIdx.x;
    if (t >= 250) return;
    const int l = s * 250 + t;

    unsigned p[8];
#pragma unroll
    for (int h = 0; h < 8; ++h) {
        float y2[2];
#pragma unroll
        for (int q = 0; q < 2; ++q) {
            const int r   = 2 * h + q;
            const int idx = (rg * RPG + r) * NLAB + l;   // coalesced in t
            const float lg  = logits[idx];
            const float lab = labels[idx];
            const float sg  = 1.0f / (1.0f + __expf(-lg));
            const bool ann  = (lab == 0.0f) || (lab == 1.0f);
            y2[q] = ann ? (2.0f * lab - 1.0f) : (2.0f * sg - 1.0f);
        }
        h2 hv;
        hv.x = (_Float16)y2[0];
        hv.y = (_Float16)y2[1];
        p[h] = __builtin_bit_cast(unsigned, hv);
    }
    ushort* dst = yPack + (size_t)rg * IMG_U16 + slot16(l);
    uint4 v0; v0.x = p[0]; v0.y = p[1]; v0.z = p[2]; v0.w = p[3];
    uint4 v1; v1.x = p[4]; v1.y = p[5]; v1.z = p[6]; v1.w = p[7];
    *(uint4*)(dst)     = v0;    // rows 0-7
    *(uint4*)(dst + 8) = v1;    // rows 8-15
}

// ---------------------------------------------------------------------------
// K2: edge reduction. 1024 threads, 64992 B LDS -> 2 blocks/CU, 32 waves/CU.
// XCD map: x = bid&7 (XCD), j = bid>>3, rg = x*8 + (j&7), es = j>>3.
// Strided layout (wave = 64 consecutive edges -> left col ~broadcast).
// NO rotating pipeline (R10's ~20 v_mov/iter): each iteration handles TWO
// independent edges -> 8 independent ds_read_b128 in flight, one waitcnt,
// 16 dot2s. ILP inside the iteration; 32 waves/CU hide index-load latency.
// ---------------------------------------------------------------------------
__global__ __launch_bounds__(1024, 8) void edge_reduce_kernel(
        const ushort* __restrict__ yPack, const float* __restrict__ ew,
        const int* __restrict__ li, const int* __restrict__ ri,
        int nEdges, float* __restrict__ partials) {
    __shared__ uint4 shv[IMG_V4];               // 64992 B
    __shared__ float red[16];
    const int x   = blockIdx.x & 7;             // XCD slot
    const int j   = blockIdx.x >> 3;
    const int rg  = x * 8 + (j & 7);
    const int es  = j >> 3;
    const int tid = threadIdx.x;

    const uint4* src = (const uint4*)(yPack + (size_t)rg * IMG_U16);
    for (int i = tid; i < IMG_V4; i += 1024) shv[i] = src[i];
    __syncthreads();
    const ushort* sh = (const ushort*)shv;

    const int per   = (nEdges + ES - 1) / ES;
    const int e0    = es * per;
    const int e1    = min(e0 + per, nEdges);
    const int niter = (per + 2047) >> 11;       // 2 edges/thread/iter, uniform

    float acc = 0.0f;
    for (int k = 0; k < niter; ++k) {
        const int ea = e0 + tid + (k << 11);
        const int eb = ea + 1024;
        int eca = min(ea, e1 - 1); if (eca < e0) eca = e0;
        int ecb = min(eb, e1 - 1); if (ecb < e0) ecb = e0;

        const int   la = li[eca], ra = ri[eca];
        const int   lb = li[ecb], rb = ri[ecb];
        const float wa = (ea < e1) ? ew[eca] : 0.0f;
        const float wb = (eb < e1) ? ew[ecb] : 0.0f;

        const int sla = slot16(la), sra = slot16(ra);
        const int slb = slot16(lb), srb = slot16(rb);
        // 8 independent LDS vector reads
        const uint4 Aa0 = *(const uint4*)(sh + sla);
        const uint4 Aa1 = *(const uint4*)(sh + sla + 8);
        const uint4 Ba0 = *(const uint4*)(sh + sra);
        const uint4 Ba1 = *(const uint4*)(sh + sra + 8);
        const uint4 Ab0 = *(const uint4*)(sh + slb);
        const uint4 Ab1 = *(const uint4*)(sh + slb + 8);
        const uint4 Bb0 = *(const uint4*)(sh + srb);
        const uint4 Bb1 = *(const uint4*)(sh + srb + 8);

        float sa = 0.0f;
        sa = dot_acc(Aa0.x, Ba0.x, sa);
        sa = dot_acc(Aa0.y, Ba0.y, sa);
        sa = dot_acc(Aa0.z, Ba0.z, sa);
        sa = dot_acc(Aa0.w, Ba0.w, sa);
        sa = dot_acc(Aa1.x, Ba1.x, sa);
        sa = dot_acc(Aa1.y, Ba1.y, sa);
        sa = dot_acc(Aa1.z, Ba1.z, sa);
        sa = dot_acc(Aa1.w, Ba1.w, sa);
        float sb = 0.0f;
        sb = dot_acc(Ab0.x, Bb0.x, sb);
        sb = dot_acc(Ab0.y, Bb0.y, sb);
        sb = dot_acc(Ab0.z, Bb0.z, sb);
        sb = dot_acc(Ab0.w, Bb0.w, sb);
        sb = dot_acc(Ab1.x, Bb1.x, sb);
        sb = dot_acc(Ab1.y, Bb1.y, sb);
        sb = dot_acc(Ab1.z, Bb1.z, sb);
        sb = dot_acc(Ab1.w, Bb1.w, sb);

        acc = fmaf(wa, sa, acc);
        acc = fmaf(wb, sb, acc);
    }

#pragma unroll
    for (int off = 32; off > 0; off >>= 1)
        acc += __shfl_down(acc, off, 64);
    if ((tid & 63) == 0) red[tid >> 6] = acc;
    __syncthreads();
    if (tid == 0) {
        float t = 0.0f;
#pragma unroll
        for (int i = 0; i < 16; ++i) t += red[i];
        partials[blockIdx.x] = t;
    }
}

// ---------------------------------------------------------------------------
// K3: sum partials, scale. Single block, fixed order -> deterministic.
// ---------------------------------------------------------------------------
__global__ __launch_bounds__(512) void final_reduce_kernel(
        const float* __restrict__ partials, int n, float scale,
        float* __restrict__ out) {
    float s = 0.0f;
    for (int i = threadIdx.x; i < n; i += blockDim.x) s += partials[i];
#pragma unroll
    for (int off = 32; off > 0; off >>= 1)
        s += __shfl_down(s, off, 64);

    __shared__ float smem[8];
    const int wave = threadIdx.x >> 6;
    const int lane = threadIdx.x & 63;
    if (lane == 0) smem[wave] = s;
    __syncthreads();
    if (threadIdx.x == 0) {
        float t = 0.0f;
        for (int i = 0; i < (int)(blockDim.x >> 6); ++i) t += smem[i];
        out[0] = scale * t;
    }
}

// ---------------------------------------------------------------------------
extern "C" void kernel_launch(void* const* d_in, const int* in_sizes, int n_in,
                              void* d_out, int out_size, void* d_ws, size_t ws_size,
                              hipStream_t stream) {
    const float* logits = (const float*)d_in[0];
    const float* labels = (const float*)d_in[1];
    const float* ew     = (const float*)d_in[2];
    const int*   li     = (const int*)d_in[3];
    const int*   ri     = (const int*)d_in[4];
    float* out          = (float*)d_out;

    const int nEdges = in_sizes[2];

    // workspace: yPack images (64 * 64992 B = 4.16 MB), partials (2 KB)
    ushort* yPack    = (ushort*)d_ws;
    float*  partials = (float*)((char*)d_ws + (size_t)NRG * IMG_U16 * sizeof(ushort));

    convert_pack_kernel<<<NRG * 8, 256, 0, stream>>>(logits, labels, yPack);

    edge_reduce_kernel<<<NB2, 1024, 0, stream>>>(yPack, ew, li, ri, nEdges, partials);

    const float scale = LAMBDA_SMOOTH / ((float)BATCH * (float)nEdges);
    final_reduce_kernel<<<1, 512, 0, stream>>>(partials, NB2, scale, out);
}